// Round 5
// baseline (269.598 us; speedup 1.0000x reference)
//
#include <hip/hip_runtime.h>
#include <hip/hip_bf16.h>
#include <stdint.h>

// HausdorffLoss: N=M=4096, D=1024 fp32 in, scalar fp32 out.
// SINGLE fused kernel: prepass (fp32->bf16 + norms) -> grid spin-barrier ->
// bf16 MFMA GEMM (256x256 tile, 8 waves, quadrant-phase schedule, 2-buffer
// LDS, counted vmcnt(4)/K-tile) with fused min epilogue -> last-block mean.
// 256 blocks x 512 threads, 128KB LDS => exactly 1 block/CU => co-resident.

#define NPTS 4096
#define MPTS 4096
#define DDIM 1024

typedef __attribute__((ext_vector_type(8))) short bf16x8;
typedef __attribute__((ext_vector_type(4))) float f32x4;
typedef __attribute__((ext_vector_type(4))) unsigned short us4;

__device__ __forceinline__ unsigned short f2bf(float f) {
    unsigned int u = __float_as_uint(f);
    unsigned int r = 0x7FFFu + ((u >> 16) & 1u);   // RNE
    return (unsigned short)((u + r) >> 16);
}

__device__ __forceinline__ void gl_lds16(const void* g, void* l) {
    __builtin_amdgcn_global_load_lds(
        (const __attribute__((address_space(1))) unsigned int*)g,
        (__attribute__((address_space(3))) unsigned int*)l, 16, 0, 0);
}

// LDS buffer (64KB each, 2 buffers): A rows 0..255 at +0 (128B/row, XOR-
// swizzled chunks), B cols 0..255 at +32768. Half regions (16KB):
// A-rows0-127=+0, A-rows128-255=+16384, B-cols0-127=+32768, B-cols128-255=+49152.

#define STAGE_H(ldsBase, gRowBase, kcol) do {                                   \
    gl_lds16((gRowBase) + (size_t)(wave * 8 + srow) * DDIM + (kcol) + schoff,   \
             ldsb + (ldsBase) + wave * 1024);                                   \
    gl_lds16((gRowBase) + (size_t)(64 + wave * 8 + srow) * DDIM + (kcol) + schoff, \
             ldsb + (ldsBase) + 8192 + wave * 1024);                            \
} while (0)

#define RD_A(CURB, aq) do {                                                     \
    _Pragma("unroll")                                                           \
    for (int fl_ = 0; fl_ < 4; ++fl_) {                                         \
        const int row_ = wr * 128 + (aq) * 64 + fl_ * 16 + r0;                  \
        af[fl_][0] = *(const bf16x8*)(ldsb + (CURB) + row_ * 128 + ch0);        \
        af[fl_][1] = *(const bf16x8*)(ldsb + (CURB) + row_ * 128 + ch1);        \
    }                                                                           \
} while (0)

#define RD_B(CURB, bq, dst) do {                                                \
    _Pragma("unroll")                                                           \
    for (int fj_ = 0; fj_ < 2; ++fj_) {                                         \
        const int col_ = wc * 64 + (bq) * 32 + fj_ * 16 + r0;                   \
        dst[fj_][0] = *(const bf16x8*)(ldsb + (CURB) + 32768 + col_ * 128 + ch0); \
        dst[fj_][1] = *(const bf16x8*)(ldsb + (CURB) + 32768 + col_ * 128 + ch1); \
    }                                                                           \
} while (0)

#define MFMA_Q(aq, bq, BF)                                                      \
    _Pragma("unroll")                                                           \
    for (int fl_ = 0; fl_ < 4; ++fl_) {                                         \
        _Pragma("unroll")                                                       \
        for (int fj_ = 0; fj_ < 2; ++fj_) {                                     \
            acc[(aq) * 4 + fl_][(bq) * 2 + fj_] =                               \
                __builtin_amdgcn_mfma_f32_16x16x32_bf16(af[fl_][0], BF[fj_][0], \
                    acc[(aq) * 4 + fl_][(bq) * 2 + fj_], 0, 0, 0);              \
            acc[(aq) * 4 + fl_][(bq) * 2 + fj_] =                               \
                __builtin_amdgcn_mfma_f32_16x16x32_bf16(af[fl_][1], BF[fj_][1], \
                    acc[(aq) * 4 + fl_][(bq) * 2 + fj_], 0, 0, 0);              \
        }                                                                       \
    }

#define BARRIER_MFMA(aq, bq, BF, WAITSTMT) do {                                 \
    __builtin_amdgcn_s_barrier();                                               \
    asm volatile("s_waitcnt lgkmcnt(0)" ::: "memory");                          \
    __builtin_amdgcn_sched_barrier(0);                                          \
    __builtin_amdgcn_s_setprio(1);                                              \
    MFMA_Q(aq, bq, BF);                                                         \
    __builtin_amdgcn_s_setprio(0);                                              \
    WAITSTMT;                                                                   \
    __builtin_amdgcn_s_barrier();                                               \
} while (0)

#define TILE(t, CURB, NXTB) do {                                                \
    const int kN1_ = ((t) + 1) * 64, kN2_ = ((t) + 2) * 64;                     \
    RD_A(CURB, 0); RD_B(CURB, 0, bf0);                                          \
    if ((t) + 1 < 16) STAGE_H((NXTB) + 49152, Bb + 128 * DDIM, kN1_);           \
    BARRIER_MFMA(0, 0, bf0, );                                                  \
    RD_B(CURB, 1, bf1);                                                         \
    if ((t) + 1 < 16) STAGE_H((NXTB) + 16384, Ab + 128 * DDIM, kN1_);           \
    BARRIER_MFMA(0, 1, bf1, );                                                  \
    RD_A(CURB, 1);                                                              \
    if ((t) + 2 < 16) STAGE_H((CURB) + 32768, Bb, kN2_);                        \
    BARRIER_MFMA(1, 1, bf1, );                                                  \
    if ((t) + 2 < 16) STAGE_H((CURB) + 0, Ab, kN2_);                            \
    BARRIER_MFMA(1, 0, bf0,                                                     \
        if ((t) < 14) { asm volatile("s_waitcnt vmcnt(4)" ::: "memory"); }      \
        else if ((t) == 14) { asm volatile("s_waitcnt vmcnt(0)" ::: "memory"); });\
} while (0)

__global__ __launch_bounds__(512, 2) void cham_fused_kernel(
    const float* __restrict__ s1, const float* __restrict__ s2,
    unsigned short* __restrict__ b1, unsigned short* __restrict__ b2,
    float* __restrict__ norms,        // [8192]: x2 ++ y2
    unsigned int* __restrict__ mins,  // [8192]: rowmin ++ colmin
    unsigned int* __restrict__ ctrs,  // [2]: grid barrier, done counter
    float* __restrict__ out) {
    __shared__ __align__(16) char lds[131072];
    char* ldsb = lds;
    unsigned int* rowmin = mins;
    unsigned int* colmin = mins + NPTS;

    const int tid = threadIdx.x;
    const int wave = tid >> 6;
    const int lane = tid & 63;

    // ================= phase A: prepass (32 rows per block) =================
    {
        #pragma unroll
        for (int rr = 0; rr < 4; ++rr) {
            const int row = blockIdx.x * 32 + wave * 4 + rr;
            const float* src;
            unsigned short* dst;
            if (row < NPTS) { src = s1 + (size_t)row * DDIM; dst = b1 + (size_t)row * DDIM; }
            else            { src = s2 + (size_t)(row - NPTS) * DDIM; dst = b2 + (size_t)(row - NPTS) * DDIM; }
            float sq = 0.f;
            #pragma unroll
            for (int i = 0; i < 4; ++i) {
                float4 v = ((const float4*)src)[lane + i * 64];
                sq += v.x * v.x + v.y * v.y + v.z * v.z + v.w * v.w;
                us4 o;
                o.x = f2bf(v.x); o.y = f2bf(v.y); o.z = f2bf(v.z); o.w = f2bf(v.w);
                ((us4*)dst)[lane + i * 64] = o;
            }
            #pragma unroll
            for (int off = 32; off; off >>= 1) sq += __shfl_down(sq, off, 64);
            if (lane == 0) { norms[row] = sq; mins[row] = 0x7f7f7f7fu; }
        }
    }

    // ================= grid spin-barrier (all 256 blocks co-resident) =======
    __threadfence();
    __syncthreads();
    if (tid == 0) {
        __hip_atomic_fetch_add(&ctrs[0], 1u, __ATOMIC_ACQ_REL, __HIP_MEMORY_SCOPE_AGENT);
        while (__hip_atomic_load(&ctrs[0], __ATOMIC_ACQUIRE, __HIP_MEMORY_SCOPE_AGENT) < 256u) {
            __builtin_amdgcn_s_sleep(2);
        }
    }
    __syncthreads();
    __threadfence();

    // ================= phase B: GEMM (R3 schedule, linear mapping) ==========
    const int bi = blockIdx.x & 15;
    const int bj = blockIdx.x >> 4;
    const int wr = wave >> 2;          // 0..1 (128 rows)
    const int wc = wave & 3;           // 0..3 (64 cols)
    const int r0 = lane & 15;
    const int q = lane >> 4;           // 0..3

    const int ch0 = ((q ^ (r0 & 7)) << 4);
    const int ch1 = (((4 + q) ^ (r0 & 7)) << 4);
    const int srow = lane >> 3;
    const int schoff = (((lane & 7) ^ srow) * 8);

    const unsigned short* Ab = b1 + (size_t)(bi * 256) * DDIM;
    const unsigned short* Bb = b2 + (size_t)(bj * 256) * DDIM;

    f32x4 acc[8][4];
    #pragma unroll
    for (int i = 0; i < 8; ++i)
        #pragma unroll
        for (int j = 0; j < 4; ++j)
            acc[i][j] = (f32x4){0.f, 0.f, 0.f, 0.f};

    bf16x8 af[4][2], bf0[2][2], bf1[2][2];

    STAGE_H(0 + 32768, Bb, 0);
    STAGE_H(0 + 0, Ab, 0);
    STAGE_H(0 + 49152, Bb + 128 * DDIM, 0);
    STAGE_H(0 + 16384, Ab + 128 * DDIM, 0);
    STAGE_H(65536 + 32768, Bb, 64);
    STAGE_H(65536 + 0, Ab, 64);
    asm volatile("s_waitcnt vmcnt(4)" ::: "memory");
    __builtin_amdgcn_s_barrier();

    for (int tt = 0; tt < 8; ++tt) {
        const int te = 2 * tt, to = 2 * tt + 1;
        TILE(te, 0, 65536);
        TILE(to, 65536, 0);
    }

    // ---- epilogue: dist = (x2[n] + y2[m] - 2*xy)/D, fused row/col mins
    const float invD = 1.0f / (float)DDIM;
    const int nb = bi * 256 + wr * 128;
    const int mb = bj * 256 + wc * 64;
    const float* x2 = norms;
    const float* y2 = norms + NPTS;

    float y2v[4];
    #pragma unroll
    for (int fj = 0; fj < 4; ++fj)
        y2v[fj] = y2[mb + (fj >> 1) * 32 + (fj & 1) * 16 + r0];

    float cv[4];
    #pragma unroll
    for (int fj = 0; fj < 4; ++fj) cv[fj] = 3.0e38f;

    #pragma unroll
    for (int fi = 0; fi < 8; ++fi) {
        #pragma unroll
        for (int rg = 0; rg < 4; ++rg) {
            const int n = nb + fi * 16 + q * 4 + rg;
            const float x2v = x2[n];
            float rv = 3.0e38f;
            #pragma unroll
            for (int fj = 0; fj < 4; ++fj) {
                float d = (x2v + y2v[fj] - 2.0f * acc[fi][fj][rg]) * invD;
                rv = fminf(rv, d);
                cv[fj] = fminf(cv[fj], d);
            }
            rv = fminf(rv, __shfl_xor(rv, 1, 64));
            rv = fminf(rv, __shfl_xor(rv, 2, 64));
            rv = fminf(rv, __shfl_xor(rv, 4, 64));
            rv = fminf(rv, __shfl_xor(rv, 8, 64));
            if (r0 == 0) atomicMin(&rowmin[n], __float_as_uint(rv));
        }
    }

    #pragma unroll
    for (int fj = 0; fj < 4; ++fj) {
        float v = cv[fj];
        v = fminf(v, __shfl_xor(v, 16, 64));
        v = fminf(v, __shfl_xor(v, 32, 64));
        if (lane < 16)
            atomicMin(&colmin[mb + (fj >> 1) * 32 + (fj & 1) * 16 + lane],
                      __float_as_uint(v));
    }

    // ================= phase C: last block computes the mean ================
    __threadfence();
    __syncthreads();
    __shared__ unsigned int lastflag;
    if (tid == 0)
        lastflag = __hip_atomic_fetch_add(&ctrs[1], 1u, __ATOMIC_ACQ_REL,
                                          __HIP_MEMORY_SCOPE_AGENT);
    __syncthreads();
    if (lastflag == 255u) {
        __threadfence();
        float s = 0.f;
        #pragma unroll
        for (int i = 0; i < 16; ++i)
            s += __uint_as_float(__hip_atomic_load(&mins[tid + i * 512],
                    __ATOMIC_RELAXED, __HIP_MEMORY_SCOPE_AGENT));
        #pragma unroll
        for (int off = 32; off; off >>= 1) s += __shfl_down(s, off, 64);
        float* red = (float*)(ldsb + 64);
        if (lane == 0) red[wave] = s;
        __syncthreads();
        if (tid == 0) {
            float tot = 0.f;
            #pragma unroll
            for (int i = 0; i < 8; ++i) tot += red[i];
            out[0] = tot * (1.0f / 8192.0f);
        }
    }
}

extern "C" void kernel_launch(void* const* d_in, const int* in_sizes, int n_in,
                              void* d_out, int out_size, void* d_ws, size_t ws_size,
                              hipStream_t stream) {
    const float* s1 = (const float*)d_in[0];
    const float* s2 = (const float*)d_in[1];
    char* ws = (char*)d_ws;

    unsigned short* b1 = (unsigned short*)ws;                         //  8 MB
    unsigned short* b2 = (unsigned short*)(ws + 8388608);             //  8 MB
    float* norms       = (float*)(ws + 16777216);                     // 32 KB
    unsigned int* mins = (unsigned int*)(ws + 16777216 + 32768);      // 32 KB
    unsigned int* ctrs = (unsigned int*)(ws + 16777216 + 65536);      //  8 B
    float* out = (float*)d_out;

    hipMemsetAsync(ctrs, 0, 8, stream);
    cham_fused_kernel<<<256, 512, 0, stream>>>(s1, s2, b1, b2, norms, mins,
                                               ctrs, out);
}

// Round 6
// 130.450 us; speedup vs baseline: 2.0667x; 2.0667x over previous
//
#include <hip/hip_runtime.h>
#include <hip/hip_bf16.h>
#include <stdint.h>

// HausdorffLoss: N=M=4096, D=1024 fp32 in, scalar fp32 out.
// R6: prepass kernel (fp32->bf16 + norms + min-init) -> GEMM kernel
// (R3 quadrant-phase schedule, XCD-chunked swizzle, fused fence-free
// last-block reduction). Kernel boundary provides the bulk L2 writeback.

#define NPTS 4096
#define MPTS 4096
#define DDIM 1024

typedef __attribute__((ext_vector_type(8))) short bf16x8;
typedef __attribute__((ext_vector_type(4))) float f32x4;
typedef __attribute__((ext_vector_type(4))) unsigned short us4;

__device__ __forceinline__ unsigned short f2bf(float f) {
    unsigned int u = __float_as_uint(f);
    unsigned int r = 0x7FFFu + ((u >> 16) & 1u);   // RNE
    return (unsigned short)((u + r) >> 16);
}

__device__ __forceinline__ void gl_lds16(const void* g, void* l) {
    __builtin_amdgcn_global_load_lds(
        (const __attribute__((address_space(1))) unsigned int*)g,
        (__attribute__((address_space(3))) unsigned int*)l, 16, 0, 0);
}

// ---------------- prepass: fp32 -> bf16 + row squared norms + min-init -----
__global__ __launch_bounds__(256) void prepass_kernel(
    const float* __restrict__ s1, const float* __restrict__ s2,
    unsigned short* __restrict__ b1, unsigned short* __restrict__ b2,
    float* __restrict__ norms, unsigned int* __restrict__ mins) {
    const int row = blockIdx.x * 4 + (threadIdx.x >> 6);
    const int lane = threadIdx.x & 63;
    const float* src;
    unsigned short* dst;
    if (row < NPTS) { src = s1 + (size_t)row * DDIM; dst = b1 + (size_t)row * DDIM; }
    else            { src = s2 + (size_t)(row - NPTS) * DDIM; dst = b2 + (size_t)(row - NPTS) * DDIM; }
    float sq = 0.f;
    #pragma unroll
    for (int i = 0; i < 4; ++i) {
        float4 v = ((const float4*)src)[lane + i * 64];
        sq += v.x * v.x + v.y * v.y + v.z * v.z + v.w * v.w;
        us4 o;
        o.x = f2bf(v.x); o.y = f2bf(v.y); o.z = f2bf(v.z); o.w = f2bf(v.w);
        ((us4*)dst)[lane + i * 64] = o;   // plain cached store (NO nt)
    }
    #pragma unroll
    for (int off = 32; off; off >>= 1) sq += __shfl_down(sq, off, 64);
    if (lane == 0) { norms[row] = sq; mins[row] = 0x7f7f7f7fu; }
}

// ---------------- fused GEMM + min epilogue + last-block reduction ---------
// LDS (64KB each, 2 buffers): A rows 0..255 at +0 (128B/row, XOR-swizzled
// chunks), B cols 0..255 at +32768. Halves (16KB): A0=+0, A1=+16384,
// B0=+32768, B1=+49152.

#define STAGE_H(ldsBase, gRowBase, kcol) do {                                   \
    gl_lds16((gRowBase) + (size_t)(wave * 8 + srow) * DDIM + (kcol) + schoff,   \
             ldsb + (ldsBase) + wave * 1024);                                   \
    gl_lds16((gRowBase) + (size_t)(64 + wave * 8 + srow) * DDIM + (kcol) + schoff, \
             ldsb + (ldsBase) + 8192 + wave * 1024);                            \
} while (0)

#define RD_A(CURB, aq) do {                                                     \
    _Pragma("unroll")                                                           \
    for (int fl_ = 0; fl_ < 4; ++fl_) {                                         \
        const int row_ = wr * 128 + (aq) * 64 + fl_ * 16 + r0;                  \
        af[fl_][0] = *(const bf16x8*)(ldsb + (CURB) + row_ * 128 + ch0);        \
        af[fl_][1] = *(const bf16x8*)(ldsb + (CURB) + row_ * 128 + ch1);        \
    }                                                                           \
} while (0)

#define RD_B(CURB, bq, dst) do {                                                \
    _Pragma("unroll")                                                           \
    for (int fj_ = 0; fj_ < 2; ++fj_) {                                         \
        const int col_ = wc * 64 + (bq) * 32 + fj_ * 16 + r0;                   \
        dst[fj_][0] = *(const bf16x8*)(ldsb + (CURB) + 32768 + col_ * 128 + ch0); \
        dst[fj_][1] = *(const bf16x8*)(ldsb + (CURB) + 32768 + col_ * 128 + ch1); \
    }                                                                           \
} while (0)

#define MFMA_Q(aq, bq, BF)                                                      \
    _Pragma("unroll")                                                           \
    for (int fl_ = 0; fl_ < 4; ++fl_) {                                         \
        _Pragma("unroll")                                                       \
        for (int fj_ = 0; fj_ < 2; ++fj_) {                                     \
            acc[(aq) * 4 + fl_][(bq) * 2 + fj_] =                               \
                __builtin_amdgcn_mfma_f32_16x16x32_bf16(af[fl_][0], BF[fj_][0], \
                    acc[(aq) * 4 + fl_][(bq) * 2 + fj_], 0, 0, 0);              \
            acc[(aq) * 4 + fl_][(bq) * 2 + fj_] =                               \
                __builtin_amdgcn_mfma_f32_16x16x32_bf16(af[fl_][1], BF[fj_][1], \
                    acc[(aq) * 4 + fl_][(bq) * 2 + fj_], 0, 0, 0);              \
        }                                                                       \
    }

#define BARRIER_MFMA(aq, bq, BF, WAITSTMT) do {                                 \
    __builtin_amdgcn_s_barrier();                                               \
    asm volatile("s_waitcnt lgkmcnt(0)" ::: "memory");                          \
    __builtin_amdgcn_sched_barrier(0);                                          \
    __builtin_amdgcn_s_setprio(1);                                              \
    MFMA_Q(aq, bq, BF);                                                         \
    __builtin_amdgcn_s_setprio(0);                                              \
    WAITSTMT;                                                                   \
    __builtin_amdgcn_s_barrier();                                               \
} while (0)

#define TILE(t, CURB, NXTB) do {                                                \
    const int kN1_ = ((t) + 1) * 64, kN2_ = ((t) + 2) * 64;                     \
    RD_A(CURB, 0); RD_B(CURB, 0, bf0);                                          \
    if ((t) + 1 < 16) STAGE_H((NXTB) + 49152, Bb + 128 * DDIM, kN1_);           \
    BARRIER_MFMA(0, 0, bf0, );                                                  \
    RD_B(CURB, 1, bf1);                                                         \
    if ((t) + 1 < 16) STAGE_H((NXTB) + 16384, Ab + 128 * DDIM, kN1_);           \
    BARRIER_MFMA(0, 1, bf1, );                                                  \
    RD_A(CURB, 1);                                                              \
    if ((t) + 2 < 16) STAGE_H((CURB) + 32768, Bb, kN2_);                        \
    BARRIER_MFMA(1, 1, bf1, );                                                  \
    if ((t) + 2 < 16) STAGE_H((CURB) + 0, Ab, kN2_);                            \
    BARRIER_MFMA(1, 0, bf0,                                                     \
        if ((t) < 14) { asm volatile("s_waitcnt vmcnt(4)" ::: "memory"); }      \
        else if ((t) == 14) { asm volatile("s_waitcnt vmcnt(0)" ::: "memory"); });\
} while (0)

__global__ __launch_bounds__(512, 2) void cham_gemm_kernel(
    const unsigned short* __restrict__ A,
    const unsigned short* __restrict__ B,
    const float* __restrict__ x2, const float* __restrict__ y2,
    unsigned int* __restrict__ mins,   // [8192]: rowmin ++ colmin
    unsigned int* __restrict__ ctr, float* __restrict__ out) {
    __shared__ __align__(16) char lds[131072];
    char* ldsb = lds;
    unsigned int* rowmin = mins;
    unsigned int* colmin = mins + NPTS;

    // XCD-chunked bijective swizzle (round-robin dispatch assumed):
    // 256 blocks = 8 XCDs x 32; each XCD gets a 4(bi) x 8(bj) rectangle
    // -> per-XCD operand set = 12 panels (~6 MB), FETCH 37->~25 MB (R4).
    const int g = blockIdx.x;
    const int xcd = g & 7;
    const int s = g >> 3;
    const int bi = (xcd >> 1) * 4 + (s >> 3);
    const int bj = (xcd & 1) * 8 + (s & 7);

    const int tid = threadIdx.x;
    const int wave = tid >> 6;
    const int lane = tid & 63;
    const int wr = wave >> 2;          // 0..1 (128 rows)
    const int wc = wave & 3;           // 0..3 (64 cols)
    const int r0 = lane & 15;
    const int q = lane >> 4;           // 0..3

    const int ch0 = ((q ^ (r0 & 7)) << 4);
    const int ch1 = (((4 + q) ^ (r0 & 7)) << 4);
    const int srow = lane >> 3;
    const int schoff = (((lane & 7) ^ srow) * 8);

    const unsigned short* Ab = A + (size_t)(bi * 256) * DDIM;
    const unsigned short* Bb = B + (size_t)(bj * 256) * DDIM;

    f32x4 acc[8][4];
    #pragma unroll
    for (int i = 0; i < 8; ++i)
        #pragma unroll
        for (int j = 0; j < 4; ++j)
            acc[i][j] = (f32x4){0.f, 0.f, 0.f, 0.f};

    bf16x8 af[4][2], bf0[2][2], bf1[2][2];

    STAGE_H(0 + 32768, Bb, 0);
    STAGE_H(0 + 0, Ab, 0);
    STAGE_H(0 + 49152, Bb + 128 * DDIM, 0);
    STAGE_H(0 + 16384, Ab + 128 * DDIM, 0);
    STAGE_H(65536 + 32768, Bb, 64);
    STAGE_H(65536 + 0, Ab, 64);
    asm volatile("s_waitcnt vmcnt(4)" ::: "memory");
    __builtin_amdgcn_s_barrier();

    for (int tt = 0; tt < 8; ++tt) {
        const int te = 2 * tt, to = 2 * tt + 1;
        TILE(te, 0, 65536);
        TILE(to, 65536, 0);
    }

    // ---- epilogue: dist = (x2[n] + y2[m] - 2*xy)/D, fused row/col mins
    const float invD = 1.0f / (float)DDIM;
    const int nb = bi * 256 + wr * 128;
    const int mb = bj * 256 + wc * 64;

    float y2v[4];
    #pragma unroll
    for (int fj = 0; fj < 4; ++fj)
        y2v[fj] = y2[mb + (fj >> 1) * 32 + (fj & 1) * 16 + r0];

    float cv[4];
    #pragma unroll
    for (int fj = 0; fj < 4; ++fj) cv[fj] = 3.0e38f;

    #pragma unroll
    for (int fi = 0; fi < 8; ++fi) {
        #pragma unroll
        for (int rg = 0; rg < 4; ++rg) {
            const int n = nb + fi * 16 + q * 4 + rg;
            const float x2v = x2[n];
            float rv = 3.0e38f;
            #pragma unroll
            for (int fj = 0; fj < 4; ++fj) {
                float d = (x2v + y2v[fj] - 2.0f * acc[fi][fj][rg]) * invD;
                rv = fminf(rv, d);
                cv[fj] = fminf(cv[fj], d);
            }
            rv = fminf(rv, __shfl_xor(rv, 1, 64));
            rv = fminf(rv, __shfl_xor(rv, 2, 64));
            rv = fminf(rv, __shfl_xor(rv, 4, 64));
            rv = fminf(rv, __shfl_xor(rv, 8, 64));
            if (r0 == 0) atomicMin(&rowmin[n], __float_as_uint(rv));
        }
    }

    #pragma unroll
    for (int fj = 0; fj < 4; ++fj) {
        float v = cv[fj];
        v = fminf(v, __shfl_xor(v, 16, 64));
        v = fminf(v, __shfl_xor(v, 32, 64));
        if (lane < 16)
            atomicMin(&colmin[mb + (fj >> 1) * 32 + (fj & 1) * 16 + lane],
                      __float_as_uint(v));
    }

    // ---- last block computes the mean. NO threadfence (no L2 storm):
    // device-scope atomics hit the coherent point; __syncthreads drains
    // each wave's outstanding atomics (vmcnt) before the counter bump.
    __syncthreads();
    __shared__ unsigned int lastflag;
    if (tid == 0)
        lastflag = __hip_atomic_fetch_add(&ctr[0], 1u, __ATOMIC_ACQUIRE,
                                          __HIP_MEMORY_SCOPE_AGENT);
    __syncthreads();
    if (lastflag == 255u) {
        float sum = 0.f;
        #pragma unroll
        for (int i = 0; i < 16; ++i)
            sum += __uint_as_float(__hip_atomic_load(&mins[tid + i * 512],
                    __ATOMIC_RELAXED, __HIP_MEMORY_SCOPE_AGENT));
        #pragma unroll
        for (int off = 32; off; off >>= 1) sum += __shfl_down(sum, off, 64);
        float* red = (float*)(ldsb + 64);
        if (lane == 0) red[wave] = sum;
        __syncthreads();
        if (tid == 0) {
            float tot = 0.f;
            #pragma unroll
            for (int i = 0; i < 8; ++i) tot += red[i];
            out[0] = tot * (1.0f / 8192.0f);
        }
    }
}

extern "C" void kernel_launch(void* const* d_in, const int* in_sizes, int n_in,
                              void* d_out, int out_size, void* d_ws, size_t ws_size,
                              hipStream_t stream) {
    const float* s1 = (const float*)d_in[0];
    const float* s2 = (const float*)d_in[1];
    char* ws = (char*)d_ws;

    unsigned short* b1 = (unsigned short*)ws;                         //  8 MB
    unsigned short* b2 = (unsigned short*)(ws + 8388608);             //  8 MB
    float* norms       = (float*)(ws + 16777216);                     // 32 KB
    unsigned int* mins = (unsigned int*)(ws + 16777216 + 32768);      // 32 KB
    unsigned int* ctr  = (unsigned int*)(ws + 16777216 + 65536);      //  4 B
    float* out = (float*)d_out;

    hipMemsetAsync(ctr, 0, 4, stream);
    prepass_kernel<<<2048, 256, 0, stream>>>(s1, s2, b1, b2, norms, mins);
    cham_gemm_kernel<<<256, 512, 0, stream>>>(b1, b2, norms, norms + NPTS,
                                              mins, ctr, out);
}